// Round 1
// baseline (28359.607 us; speedup 1.0000x reference)
//
#include <hip/hip_runtime.h>
#include <stdint.h>

// LSTMClassifier: 2-layer LSTM (B=128,T=1024,I=256,H=512) + FC(512->1).
// Persistent grid-resident kernel, layers pipelined (layer1 lags 1 step),
// weights resident in VGPRs as MFMA B-fragments, 1 grid barrier per macro-step.
//
// ws layout (bytes), total ~7.6MB:
//   Wp0 [2048][768]  bf16 packed rows r=u*4+q  (cols: 0..255=W_ih0, 256..767=W_hh0)
//   Wp1 [2048][1024] bf16 packed                (cols: 0..511=W_ih1, 512..1023=W_hh1)
//   bp0/bp1 [2048] f32 (b_ih+b_hh, packed order)
//   h    ushort[4][128*512]: h0[0],h0[1],h1[0],h1[1] (ping-pong per macro-step)
//   cnt  barrier counter

#define T_STEPS 1024
#define NBLK 512
#define NTHR 256

#define WS_WP0   0u
#define WS_WP1   3145728u
#define WS_BP0   7340032u
#define WS_BP1   7348224u
#define WS_H     7356416u
#define WS_CNT   7880704u

typedef __bf16 bf16x8 __attribute__((ext_vector_type(8)));
typedef float  f32x4  __attribute__((ext_vector_type(4)));

__device__ __forceinline__ unsigned short f2bf(float f) {
    union { float f; uint32_t u; } a; a.f = f;
    uint32_t r = a.u + 0x7fffu + ((a.u >> 16) & 1u);
    return (unsigned short)(r >> 16);
}
__device__ __forceinline__ float bf2f(unsigned short u) {
    union { uint32_t u; float f; } a; a.u = ((uint32_t)u) << 16; return a.f;
}
__device__ __forceinline__ float sigm(float x)  { return 1.f / (1.f + __expf(-x)); }
__device__ __forceinline__ float tanh_f(float x){ return 2.f / (1.f + __expf(-2.f * x)) - 1.f; }

// ---- pre-pack weights to bf16, gate-interleaved rows r = u*4 + q (q: i,f,g,o) ----
__global__ void k_pack(const float* __restrict__ Wih0, const float* __restrict__ Whh0,
                       const float* __restrict__ Wih1, const float* __restrict__ Whh1,
                       unsigned short* __restrict__ Wp0, unsigned short* __restrict__ Wp1)
{
    int t = blockIdx.x * blockDim.x + threadIdx.x;
    const int N0 = 2048 * 768;
    const int N1 = 2048 * 1024;
    if (t < N0) {
        int r = t / 768, k = t - r * 768;
        int u = r >> 2, q = r & 3, row = q * 512 + u;
        float v = (k < 256) ? Wih0[row * 256 + k] : Whh0[row * 512 + (k - 256)];
        Wp0[t] = f2bf(v);
    } else if (t < N0 + N1) {
        int t2 = t - N0;
        int r = t2 >> 10, k = t2 & 1023;
        int u = r >> 2, q = r & 3, row = q * 512 + u;
        float v = (k < 512) ? Wih1[row * 512 + k] : Whh1[row * 512 + (k - 512)];
        Wp1[t2] = f2bf(v);
    }
}

// ---- biases (packed), zero h ping-pong buffers, zero barrier counter ----
__global__ void k_misc(const float* __restrict__ bih0, const float* __restrict__ bhh0,
                       const float* __restrict__ bih1, const float* __restrict__ bhh1,
                       float* __restrict__ bp0, float* __restrict__ bp1,
                       unsigned short* __restrict__ hbufs, unsigned* __restrict__ cnt)
{
    int t = blockIdx.x * blockDim.x + threadIdx.x;
    if (t < 2048) {
        int u = t >> 2, q = t & 3, row = q * 512 + u;
        bp0[t] = bih0[row] + bhh0[row];
    } else if (t < 4096) {
        int r = t - 2048; int u = r >> 2, q = r & 3, row = q * 512 + u;
        bp1[r] = bih1[row] + bhh1[row];
    } else if (t < 4096 + 262144) {
        hbufs[t - 4096] = 0;
    } else if (t == 4096 + 262144) {
        *cnt = 0;
    }
}

// ---- persistent LSTM ----
// NKW: ksteps(32) per wave; KTOT: total K; KS: boundary src0/src1; L0: layer-0 flag
template<int NKW, int KTOT, int KS, bool L0>
__device__ __forceinline__ void run_layer(
    int b0, int ut0, int g0, int w, int col, int quad, int tid,
    const float* __restrict__ x,
    const unsigned short* __restrict__ Wp,
    const float* __restrict__ bp,
    unsigned short* h00, unsigned short* h01,
    unsigned short* h10, unsigned short* h11,
    unsigned* cnt,
    float (*red)[16][68])
{
    const int bA = b0 + col;  // A-fragment row (batch index)

    // B fragments (weights) -> VGPR-resident for the whole run.
    // B[k][n]: n=lane&15 (packed gate row within 16-tile), k=quad*8+j -> 16B row-major loads.
    bf16x8 Bf[4][NKW];
    #pragma unroll
    for (int f = 0; f < 4; ++f) {
        const unsigned short* wrow = Wp + (g0 + f * 16 + col) * KTOT + w * (NKW * 32) + quad * 8;
        #pragma unroll
        for (int ks = 0; ks < NKW; ++ks)
            Bf[f][ks] = __builtin_bit_cast(bf16x8, *(const uint4*)(wrow + ks * 32));
    }

    const int bl = tid >> 4, ul = tid & 15;      // elementwise domain: 16 batch x 16 units
    const f32x4 bias = *(const f32x4*)(bp + g0 + ul * 4);
    float c = 0.f;                               // cell state, register-resident

    // Per-kstep A source offsets (frag never straddles the KS boundary: 32 | KS)
    int  offA[NKW];
    bool s0[NKW];
    #pragma unroll
    for (int ks = 0; ks < NKW; ++ks) {
        int kg = w * (NKW * 32) + ks * 32 + quad * 8;
        if (kg < KS) { s0[ks] = true;  offA[ks] = L0 ? (bA * (T_STEPS * 256) + kg) : (bA * 512 + kg); }
        else         { s0[ks] = false; offA[ks] = bA * 512 + (kg - KS); }
    }

    unsigned short* h0b[2] = { h00, h01 };
    unsigned short* h1b[2] = { h10, h11 };
    int rp = 0;

    for (int s = 0; s <= T_STEPS; ++s) {
        const bool active = L0 ? (s < T_STEPS) : (s >= 1);
        const unsigned short* h0r = h0b[rp];
        const unsigned short* h1r = h1b[rp];

        if (active) {
            const int t = L0 ? s : (s - 1);
            bf16x8 Af[NKW];
            if (L0) {
                const float* xb = x + t * 256;
                #pragma unroll
                for (int ks = 0; ks < NKW; ++ks) {
                    if (s0[ks]) {   // x source: fp32 -> bf16 on the fly
                        const float* p = xb + offA[ks];
                        float4 lo = *(const float4*)p;
                        float4 hi = *(const float4*)(p + 4);
                        bf16x8 v;
                        v[0]=(__bf16)lo.x; v[1]=(__bf16)lo.y; v[2]=(__bf16)lo.z; v[3]=(__bf16)lo.w;
                        v[4]=(__bf16)hi.x; v[5]=(__bf16)hi.y; v[6]=(__bf16)hi.z; v[7]=(__bf16)hi.w;
                        Af[ks] = v;
                    } else {
                        Af[ks] = __builtin_bit_cast(bf16x8, *(const uint4*)(h0r + offA[ks]));
                    }
                }
            } else {
                #pragma unroll
                for (int ks = 0; ks < NKW; ++ks) {
                    const unsigned short* p = (s0[ks] ? h0r : h1r) + offA[ks];
                    Af[ks] = __builtin_bit_cast(bf16x8, *(const uint4*)p);
                }
            }

            f32x4 acc[4] = { f32x4{0,0,0,0}, f32x4{0,0,0,0}, f32x4{0,0,0,0}, f32x4{0,0,0,0} };
            #pragma unroll
            for (int ks = 0; ks < NKW; ++ks) {
                #pragma unroll
                for (int f = 0; f < 4; ++f)
                    acc[f] = __builtin_amdgcn_mfma_f32_16x16x32_bf16(Af[ks], Bf[f][ks], acc[f], 0, 0, 0);
            }
            // Dump partials: D row=quad*4+r (batch), col=f*16+col (packed gate)
            #pragma unroll
            for (int f = 0; f < 4; ++f) {
                #pragma unroll
                for (int r = 0; r < 4; ++r)
                    red[w][quad * 4 + r][f * 16 + col] = acc[f][r];
            }
        }
        __syncthreads();
        if (active) {
            f32x4 g = bias;
            #pragma unroll
            for (int ww = 0; ww < 4; ++ww)
                g += *(const f32x4*)&red[ww][bl][ul * 4];
            float ig = sigm(g[0]), fg = sigm(g[1]), gc = tanh_f(g[2]), og = sigm(g[3]);
            c = fg * c + ig * gc;
            float h = og * tanh_f(c);
            unsigned short* hw = L0 ? h0b[rp ^ 1] : h1b[rp ^ 1];
            hw[(b0 + bl) * 512 + ut0 + ul] = f2bf(h);
        }
        __syncthreads();
        // grid barrier: monotonic counter, release on arrive, acquire fence on depart
        if (tid == 0) {
            __hip_atomic_fetch_add(cnt, 1u, __ATOMIC_RELEASE, __HIP_MEMORY_SCOPE_AGENT);
            const unsigned tgt = (unsigned)(s + 1) * NBLK;
            while (__hip_atomic_load(cnt, __ATOMIC_RELAXED, __HIP_MEMORY_SCOPE_AGENT) < tgt)
                __builtin_amdgcn_s_sleep(1);
            __builtin_amdgcn_fence(__ATOMIC_ACQUIRE, "agent");
        }
        __syncthreads();
        rp ^= 1;
    }
}

__global__ __launch_bounds__(NTHR, 2) void lstm_persistent(
    const float* __restrict__ x,
    const unsigned short* __restrict__ Wp0, const unsigned short* __restrict__ Wp1,
    const float* __restrict__ bp0, const float* __restrict__ bp1,
    unsigned short* __restrict__ hb, unsigned* __restrict__ cnt)
{
    __shared__ alignas(16) float red[4][16][68];   // 4 K-split waves x [16b][64g(+pad)]
    const int bid   = blockIdx.x;
    const int layer = bid & 1;          // interleave layers across CUs
    const int idx   = bid >> 1;         // 0..255: 8 batch-tiles x 32 unit-tiles
    const int b0    = (idx & 7) * 16;
    const int gt    = idx >> 3;
    const int ut0   = gt * 16;
    const int g0    = gt * 64;          // packed gate-row base (= ut0*4)
    const int tid   = threadIdx.x;
    const int w = tid >> 6, lane = tid & 63, col = lane & 15, quad = lane >> 4;

    unsigned short* h00 = hb;
    unsigned short* h01 = hb + 65536;
    unsigned short* h10 = hb + 131072;
    unsigned short* h11 = hb + 196608;

    if (layer == 0)
        run_layer<6, 768, 256, true >(b0, ut0, g0, w, col, quad, tid, x, Wp0, bp0, h00, h01, h10, h11, cnt, red);
    else
        run_layer<8, 1024, 512, false>(b0, ut0, g0, w, col, quad, tid, x, Wp1, bp1, h00, h01, h10, h11, cnt, red);
}

// ---- final FC head: logits[b] = h1_T[b,:] . fc_w + fc_b ----
__global__ void k_fc(const unsigned short* __restrict__ h1, const float* __restrict__ fcw,
                     const float* __restrict__ fcb, float* __restrict__ out)
{
    int b = threadIdx.x;
    if (b < 128) {
        const unsigned short* hr = h1 + b * 512;
        float acc = 0.f;
        for (int u = 0; u < 512; ++u) acc += bf2f(hr[u]) * fcw[u];
        out[b] = acc + fcb[0];
    }
}

extern "C" void kernel_launch(void* const* d_in, const int* in_sizes, int n_in,
                              void* d_out, int out_size, void* d_ws, size_t ws_size,
                              hipStream_t stream)
{
    const float* x    = (const float*)d_in[0];
    const float* Wih0 = (const float*)d_in[1];
    const float* Whh0 = (const float*)d_in[2];
    const float* bih0 = (const float*)d_in[3];
    const float* bhh0 = (const float*)d_in[4];
    const float* Wih1 = (const float*)d_in[5];
    const float* Whh1 = (const float*)d_in[6];
    const float* bih1 = (const float*)d_in[7];
    const float* bhh1 = (const float*)d_in[8];
    const float* fcw  = (const float*)d_in[9];
    const float* fcb  = (const float*)d_in[10];

    char* ws = (char*)d_ws;
    unsigned short* Wp0 = (unsigned short*)(ws + WS_WP0);
    unsigned short* Wp1 = (unsigned short*)(ws + WS_WP1);
    float* bp0 = (float*)(ws + WS_BP0);
    float* bp1 = (float*)(ws + WS_BP1);
    unsigned short* hb = (unsigned short*)(ws + WS_H);
    unsigned* cnt = (unsigned*)(ws + WS_CNT);

    const int npack = 2048 * 768 + 2048 * 1024;
    k_pack<<<(npack + 255) / 256, 256, 0, stream>>>(Wih0, Whh0, Wih1, Whh1, Wp0, Wp1);
    const int nmisc = 4096 + 262144 + 1;
    k_misc<<<(nmisc + 255) / 256, 256, 0, stream>>>(bih0, bhh0, bih1, bhh1, bp0, bp1, hb, cnt);

    lstm_persistent<<<NBLK, NTHR, 0, stream>>>(x, Wp0, Wp1, bp0, bp1, hb, cnt);

    // final h1 lands in ping-pong buffer index 1 (written at macro-step s=1024)
    k_fc<<<1, 128, 0, stream>>>(hb + 196608, fcw, fcb, (float*)d_out);
}

// Round 3
// 18344.052 us; speedup vs baseline: 1.5460x; 1.5460x over previous
//
#include <hip/hip_runtime.h>
#include <stdint.h>

// LSTMClassifier: 2-layer LSTM (B=128,T=1024,I=256,H=512) + FC(512->1).
// Persistent grid-resident kernel, layers pipelined (layer1 lags 1 step).
// R3: (a) per-batch-tile-group barriers (8 independent groups of 64 blocks,
//     8x8 tree per group) instead of one 512-wide single-counter barrier;
//     (b) weight B-fragments pinned in VGPRs via SCALAR-component empty asm
//     (aggregate "+v" on array elements doesn't compile on gfx950 backend).
//
// ws layout (bytes):
//   Wp0 [2048][768]  bf16 packed rows r=u*4+q  (cols: 0..255=W_ih0, 256..767=W_hh0)
//   Wp1 [2048][1024] bf16 packed                (cols: 0..511=W_ih1, 512..1023=W_hh1)
//   bp0/bp1 [2048] f32 (b_ih+b_hh, packed order)
//   h    ushort[4][128*512]: h0[0],h0[1],h1[0],h1[1] (ping-pong per macro-step)
//   cnt  barrier counters: 8 groups x (8 leaves + 1 root), 128B stride

#define T_STEPS 1024
#define NBLK 512
#define NTHR 256

#define WS_WP0   0u
#define WS_WP1   3145728u
#define WS_BP0   7340032u
#define WS_BP1   7348224u
#define WS_H     7356416u
#define WS_CNT   7880704u
#define CNT_U32  2304        // 72 lines x 32 u32 (128B stride)

typedef __bf16 bf16x8 __attribute__((ext_vector_type(8)));
typedef float  f32x4  __attribute__((ext_vector_type(4)));

__device__ __forceinline__ unsigned short f2bf(float f) {
    union { float f; uint32_t u; } a; a.f = f;
    uint32_t r = a.u + 0x7fffu + ((a.u >> 16) & 1u);
    return (unsigned short)(r >> 16);
}
__device__ __forceinline__ float bf2f(unsigned short u) {
    union { uint32_t u; float f; } a; a.u = ((uint32_t)u) << 16; return a.f;
}
__device__ __forceinline__ float sigm(float x)  { return 1.f / (1.f + __expf(-x)); }
__device__ __forceinline__ float tanh_f(float x){ return 2.f / (1.f + __expf(-2.f * x)) - 1.f; }

// ---- pre-pack weights to bf16, gate-interleaved rows r = u*4 + q (q: i,f,g,o) ----
__global__ void k_pack(const float* __restrict__ Wih0, const float* __restrict__ Whh0,
                       const float* __restrict__ Wih1, const float* __restrict__ Whh1,
                       unsigned short* __restrict__ Wp0, unsigned short* __restrict__ Wp1)
{
    int t = blockIdx.x * blockDim.x + threadIdx.x;
    const int N0 = 2048 * 768;
    const int N1 = 2048 * 1024;
    if (t < N0) {
        int r = t / 768, k = t - r * 768;
        int u = r >> 2, q = r & 3, row = q * 512 + u;
        float v = (k < 256) ? Wih0[row * 256 + k] : Whh0[row * 512 + (k - 256)];
        Wp0[t] = f2bf(v);
    } else if (t < N0 + N1) {
        int t2 = t - N0;
        int r = t2 >> 10, k = t2 & 1023;
        int u = r >> 2, q = r & 3, row = q * 512 + u;
        float v = (k < 512) ? Wih1[row * 512 + k] : Whh1[row * 512 + (k - 512)];
        Wp1[t2] = f2bf(v);
    }
}

// ---- biases (packed), zero h ping-pong buffers, zero barrier counters ----
__global__ void k_misc(const float* __restrict__ bih0, const float* __restrict__ bhh0,
                       const float* __restrict__ bih1, const float* __restrict__ bhh1,
                       float* __restrict__ bp0, float* __restrict__ bp1,
                       unsigned short* __restrict__ hbufs, unsigned* __restrict__ cnt)
{
    int t = blockIdx.x * blockDim.x + threadIdx.x;
    if (t < 2048) {
        int u = t >> 2, q = t & 3, row = q * 512 + u;
        bp0[t] = bih0[row] + bhh0[row];
    } else if (t < 4096) {
        int r = t - 2048; int u = r >> 2, q = r & 3, row = q * 512 + u;
        bp1[r] = bih1[row] + bhh1[row];
    } else if (t < 4096 + 262144) {
        hbufs[t - 4096] = 0;
    } else if (t < 4096 + 262144 + CNT_U32) {
        cnt[t - (4096 + 262144)] = 0;
    }
}

// ---- persistent LSTM ----
// NKW: ksteps(32) per wave; KTOT: total K; KS: boundary src0/src1; L0: layer-0 flag
template<int NKW, int KTOT, int KS, bool L0>
__device__ __forceinline__ void run_layer(
    int b0, int ut0, int g0, int w, int col, int quad, int tid,
    const float* __restrict__ x,
    const unsigned short* __restrict__ Wp,
    const float* __restrict__ bp,
    unsigned short* h00, unsigned short* h01,
    unsigned short* h10, unsigned short* h11,
    unsigned* leaf, unsigned* root,
    float (*red)[16][68])
{
    const int bA = b0 + col;  // A-fragment row (batch index)

    // B fragments (weights) -> VGPR-resident for the whole run (pinned via asm).
    // B[k][n]: n=lane&15 (packed gate row within 16-tile), k=quad*8+j.
    uint4 Bf[4][NKW];
    #pragma unroll
    for (int f = 0; f < 4; ++f) {
        const unsigned short* wrow = Wp + (g0 + f * 16 + col) * KTOT + w * (NKW * 32) + quad * 8;
        #pragma unroll
        for (int ks = 0; ks < NKW; ++ks)
            Bf[f][ks] = *(const uint4*)(wrow + ks * 32);
    }
    // Pin with scalar-component asm: opaque defs the allocator can't remat
    // from memory (aggregate/array "+v" operands fail isel on gfx950).
    #pragma unroll
    for (int f = 0; f < 4; ++f) {
        #pragma unroll
        for (int ks = 0; ks < NKW; ++ks) {
            uint32_t c0 = Bf[f][ks].x, c1 = Bf[f][ks].y, c2 = Bf[f][ks].z, c3 = Bf[f][ks].w;
            asm volatile("" : "+v"(c0), "+v"(c1), "+v"(c2), "+v"(c3));
            Bf[f][ks].x = c0; Bf[f][ks].y = c1; Bf[f][ks].z = c2; Bf[f][ks].w = c3;
        }
    }

    const int bl = tid >> 4, ul = tid & 15;      // elementwise domain: 16 batch x 16 units
    const f32x4 bias = *(const f32x4*)(bp + g0 + ul * 4);
    float c = 0.f;                               // cell state, register-resident

    // Per-kstep A source offsets (frag never straddles the KS boundary: 32 | KS)
    int  offA[NKW];
    bool s0[NKW];
    #pragma unroll
    for (int ks = 0; ks < NKW; ++ks) {
        int kg = w * (NKW * 32) + ks * 32 + quad * 8;
        if (kg < KS) { s0[ks] = true;  offA[ks] = L0 ? (bA * (T_STEPS * 256) + kg) : (bA * 512 + kg); }
        else         { s0[ks] = false; offA[ks] = bA * 512 + (kg - KS); }
    }

    unsigned short* h0b[2] = { h00, h01 };
    unsigned short* h1b[2] = { h10, h11 };
    int rp = 0;

    for (int s = 0; s <= T_STEPS; ++s) {
        const bool active = L0 ? (s < T_STEPS) : (s >= 1);
        const unsigned short* h0r = h0b[rp];
        const unsigned short* h1r = h1b[rp];

        if (active) {
            const int t = L0 ? s : (s - 1);
            bf16x8 Af[NKW];
            if (L0) {
                const float* xb = x + t * 256;
                #pragma unroll
                for (int ks = 0; ks < NKW; ++ks) {
                    if (s0[ks]) {   // x source: fp32 -> bf16 on the fly
                        const float* p = xb + offA[ks];
                        float4 lo = *(const float4*)p;
                        float4 hi = *(const float4*)(p + 4);
                        bf16x8 v;
                        v[0]=(__bf16)lo.x; v[1]=(__bf16)lo.y; v[2]=(__bf16)lo.z; v[3]=(__bf16)lo.w;
                        v[4]=(__bf16)hi.x; v[5]=(__bf16)hi.y; v[6]=(__bf16)hi.z; v[7]=(__bf16)hi.w;
                        Af[ks] = v;
                    } else {
                        Af[ks] = __builtin_bit_cast(bf16x8, *(const uint4*)(h0r + offA[ks]));
                    }
                }
            } else {
                #pragma unroll
                for (int ks = 0; ks < NKW; ++ks) {
                    const unsigned short* p = (s0[ks] ? h0r : h1r) + offA[ks];
                    Af[ks] = __builtin_bit_cast(bf16x8, *(const uint4*)p);
                }
            }

            f32x4 acc[4] = { f32x4{0,0,0,0}, f32x4{0,0,0,0}, f32x4{0,0,0,0}, f32x4{0,0,0,0} };
            #pragma unroll
            for (int ks = 0; ks < NKW; ++ks) {
                #pragma unroll
                for (int f = 0; f < 4; ++f)
                    acc[f] = __builtin_amdgcn_mfma_f32_16x16x32_bf16(
                        Af[ks], __builtin_bit_cast(bf16x8, Bf[f][ks]), acc[f], 0, 0, 0);
            }
            // Dump partials: D row=quad*4+r (batch), col=f*16+col (packed gate)
            #pragma unroll
            for (int f = 0; f < 4; ++f) {
                #pragma unroll
                for (int r = 0; r < 4; ++r)
                    red[w][quad * 4 + r][f * 16 + col] = acc[f][r];
            }
        }
        __syncthreads();
        if (active) {
            f32x4 g = bias;
            #pragma unroll
            for (int ww = 0; ww < 4; ++ww)
                g += *(const f32x4*)&red[ww][bl][ul * 4];
            float ig = sigm(g[0]), fg = sigm(g[1]), gc = tanh_f(g[2]), og = sigm(g[3]);
            c = fg * c + ig * gc;
            float h = og * tanh_f(c);
            unsigned short* hw = L0 ? h0b[rp ^ 1] : h1b[rp ^ 1];
            hw[(b0 + bl) * 512 + ut0 + ul] = f2bf(h);
        }
        __syncthreads();
        // group barrier: 8x8 tree. leaf: ACQ_REL (extends release chain of all 8),
        // last leaf arriver bumps root with RELEASE; everyone spins on root,
        // then one agent acquire fence before next step's h loads.
        if (tid == 0) {
            unsigned old = __hip_atomic_fetch_add(leaf, 1u, __ATOMIC_ACQ_REL, __HIP_MEMORY_SCOPE_AGENT);
            if ((old & 7u) == 7u)
                __hip_atomic_fetch_add(root, 1u, __ATOMIC_RELEASE, __HIP_MEMORY_SCOPE_AGENT);
            const unsigned tgt = (unsigned)(s + 1) * 8u;
            while (__hip_atomic_load(root, __ATOMIC_RELAXED, __HIP_MEMORY_SCOPE_AGENT) < tgt)
                __builtin_amdgcn_s_sleep(1);
            __builtin_amdgcn_fence(__ATOMIC_ACQUIRE, "agent");
        }
        __syncthreads();
        rp ^= 1;
    }
}

__global__ __launch_bounds__(NTHR, 2) void lstm_persistent(
    const float* __restrict__ x,
    const unsigned short* __restrict__ Wp0, const unsigned short* __restrict__ Wp1,
    const float* __restrict__ bp0, const float* __restrict__ bp1,
    unsigned short* __restrict__ hb, unsigned* __restrict__ cnt)
{
    __shared__ alignas(16) float red[4][16][68];   // 4 K-split waves x [16b][64g(+pad)]
    const int bid   = blockIdx.x;
    const int g     = bid & 7;          // batch-tile group (independent barrier domain)
    const int rest  = bid >> 3;         // 0..63: pid within group
    const int layer = rest & 1;
    const int ut    = rest >> 1;        // 0..31 unit-tile
    const int b0    = g * 16;
    const int ut0   = ut * 16;
    const int g0    = ut * 64;          // packed gate-row base (= ut0*4)
    const int tid   = threadIdx.x;
    const int w = tid >> 6, lane = tid & 63, col = lane & 15, quad = lane >> 4;

    unsigned* leaf = cnt + (g * 9 + (rest >> 3)) * 32;   // 128B-strided lines
    unsigned* root = cnt + (g * 9 + 8) * 32;

    unsigned short* h00 = hb;
    unsigned short* h01 = hb + 65536;
    unsigned short* h10 = hb + 131072;
    unsigned short* h11 = hb + 196608;

    if (layer == 0)
        run_layer<6, 768, 256, true >(b0, ut0, g0, w, col, quad, tid, x, Wp0, bp0, h00, h01, h10, h11, leaf, root, red);
    else
        run_layer<8, 1024, 512, false>(b0, ut0, g0, w, col, quad, tid, x, Wp1, bp1, h00, h01, h10, h11, leaf, root, red);
}

// ---- final FC head: logits[b] = h1_T[b,:] . fc_w + fc_b ----
__global__ void k_fc(const unsigned short* __restrict__ h1, const float* __restrict__ fcw,
                     const float* __restrict__ fcb, float* __restrict__ out)
{
    int b = threadIdx.x;
    if (b < 128) {
        const unsigned short* hr = h1 + b * 512;
        float acc = 0.f;
        for (int u = 0; u < 512; ++u) acc += bf2f(hr[u]) * fcw[u];
        out[b] = acc + fcb[0];
    }
}

extern "C" void kernel_launch(void* const* d_in, const int* in_sizes, int n_in,
                              void* d_out, int out_size, void* d_ws, size_t ws_size,
                              hipStream_t stream)
{
    const float* x    = (const float*)d_in[0];
    const float* Wih0 = (const float*)d_in[1];
    const float* Whh0 = (const float*)d_in[2];
    const float* bih0 = (const float*)d_in[3];
    const float* bhh0 = (const float*)d_in[4];
    const float* Wih1 = (const float*)d_in[5];
    const float* Whh1 = (const float*)d_in[6];
    const float* bih1 = (const float*)d_in[7];
    const float* bhh1 = (const float*)d_in[8];
    const float* fcw  = (const float*)d_in[9];
    const float* fcb  = (const float*)d_in[10];

    char* ws = (char*)d_ws;
    unsigned short* Wp0 = (unsigned short*)(ws + WS_WP0);
    unsigned short* Wp1 = (unsigned short*)(ws + WS_WP1);
    float* bp0 = (float*)(ws + WS_BP0);
    float* bp1 = (float*)(ws + WS_BP1);
    unsigned short* hb = (unsigned short*)(ws + WS_H);
    unsigned* cnt = (unsigned*)(ws + WS_CNT);

    const int npack = 2048 * 768 + 2048 * 1024;
    k_pack<<<(npack + 255) / 256, 256, 0, stream>>>(Wih0, Whh0, Wih1, Whh1, Wp0, Wp1);
    const int nmisc = 4096 + 262144 + CNT_U32;
    k_misc<<<(nmisc + 255) / 256, 256, 0, stream>>>(bih0, bhh0, bih1, bhh1, bp0, bp1, hb, cnt);

    lstm_persistent<<<NBLK, NTHR, 0, stream>>>(x, Wp0, Wp1, bp0, bp1, hb, cnt);

    // final h1 lands in ping-pong buffer index 1 (written at macro-step s=1024)
    k_fc<<<1, 128, 0, stream>>>(hb + 196608, fcw, fcb, (float*)d_out);
}

// Round 5
// 17611.998 us; speedup vs baseline: 1.6102x; 1.0416x over previous
//
#include <hip/hip_runtime.h>
#include <stdint.h>

// LSTMClassifier: 2-layer LSTM (B=128,T=1024,I=256,H=512) + FC(512->1).
// Persistent grid-resident kernel, layers pipelined (layer1 lags 1 step).
// R5: correct-by-construction sync at minimal fence count. h exchange uses
// PLAIN loads/stores; per step each block does exactly ONE release store
// (buffer_wbl2 + flag) to its private slot and ONE agent acquire fence
// (buffer_inv) after a wave-parallel poll of the group's 64 slots.
// (R4's fence-free relaxed-atomic scheme gave stale h on HW; R3's per-RMW
// ACQ_REL tree was correct but paid 9 serialized wbl2 round-trips per step.)
//
// ws layout (bytes):
//   Wp0 [2048][768]  bf16 packed rows r=u*4+q  (cols: 0..255=W_ih0, 256..767=W_hh0)
//   Wp1 [2048][1024] bf16 packed                (cols: 0..511=W_ih1, 512..1023=W_hh1)
//   bp0/bp1 [2048] f32 (b_ih+b_hh, packed order)
//   h    ushort[4][128*512]: h0[0],h0[1],h1[0],h1[1] (ping-pong per macro-step)
//   cnt  barrier slots: 8 groups x 64 dwords (one single-writer slot per block)

#define T_STEPS 1024
#define NBLK 512
#define NTHR 256

#define WS_WP0   0u
#define WS_WP1   3145728u
#define WS_BP0   7340032u
#define WS_BP1   7348224u
#define WS_H     7356416u
#define WS_CNT   7880704u
#define CNT_U32  512         // 8 groups x 64 slots

typedef __bf16 bf16x8 __attribute__((ext_vector_type(8)));
typedef float  f32x4  __attribute__((ext_vector_type(4)));

__device__ __forceinline__ unsigned short f2bf(float f) {
    union { float f; uint32_t u; } a; a.f = f;
    uint32_t r = a.u + 0x7fffu + ((a.u >> 16) & 1u);
    return (unsigned short)(r >> 16);
}
__device__ __forceinline__ float bf2f(unsigned short u) {
    union { uint32_t u; float f; } a; a.u = ((uint32_t)u) << 16; return a.f;
}
__device__ __forceinline__ float sigm(float x)  { return 1.f / (1.f + __expf(-x)); }
__device__ __forceinline__ float tanh_f(float x){ return 2.f / (1.f + __expf(-2.f * x)) - 1.f; }

// ---- pre-pack weights to bf16, gate-interleaved rows r = u*4 + q (q: i,f,g,o) ----
__global__ void k_pack(const float* __restrict__ Wih0, const float* __restrict__ Whh0,
                       const float* __restrict__ Wih1, const float* __restrict__ Whh1,
                       unsigned short* __restrict__ Wp0, unsigned short* __restrict__ Wp1)
{
    int t = blockIdx.x * blockDim.x + threadIdx.x;
    const int N0 = 2048 * 768;
    const int N1 = 2048 * 1024;
    if (t < N0) {
        int r = t / 768, k = t - r * 768;
        int u = r >> 2, q = r & 3, row = q * 512 + u;
        float v = (k < 256) ? Wih0[row * 256 + k] : Whh0[row * 512 + (k - 256)];
        Wp0[t] = f2bf(v);
    } else if (t < N0 + N1) {
        int t2 = t - N0;
        int r = t2 >> 10, k = t2 & 1023;
        int u = r >> 2, q = r & 3, row = q * 512 + u;
        float v = (k < 512) ? Wih1[row * 512 + k] : Whh1[row * 512 + (k - 512)];
        Wp1[t2] = f2bf(v);
    }
}

// ---- biases (packed), zero h ping-pong buffers, zero barrier slots ----
__global__ void k_misc(const float* __restrict__ bih0, const float* __restrict__ bhh0,
                       const float* __restrict__ bih1, const float* __restrict__ bhh1,
                       float* __restrict__ bp0, float* __restrict__ bp1,
                       unsigned short* __restrict__ hbufs, unsigned* __restrict__ cnt)
{
    int t = blockIdx.x * blockDim.x + threadIdx.x;
    if (t < 2048) {
        int u = t >> 2, q = t & 3, row = q * 512 + u;
        bp0[t] = bih0[row] + bhh0[row];
    } else if (t < 4096) {
        int r = t - 2048; int u = r >> 2, q = r & 3, row = q * 512 + u;
        bp1[r] = bih1[row] + bhh1[row];
    } else if (t < 4096 + 262144) {
        hbufs[t - 4096] = 0;
    } else if (t < 4096 + 262144 + CNT_U32) {
        cnt[t - (4096 + 262144)] = 0;
    }
}

// ---- persistent LSTM ----
// NKW: ksteps(32) per wave; KTOT: total K; KS: boundary src0/src1; L0: layer-0 flag
template<int NKW, int KTOT, int KS, bool L0>
__device__ __forceinline__ void run_layer(
    int b0, int ut0, int g0, int w, int col, int quad, int tid,
    const float* __restrict__ x,
    const unsigned short* __restrict__ Wp,
    const float* __restrict__ bp,
    unsigned short* h00, unsigned short* h01,
    unsigned short* h10, unsigned short* h11,
    unsigned* slots, int myslot,
    float (*red)[16][68])
{
    const int bA = b0 + col;  // A-fragment row (batch index)

    // B fragments (weights) -> register-resident for the whole run (pinned).
    // B[k][n]: n=lane&15 (packed gate row within 16-tile), k=quad*8+j.
    uint4 Bf[4][NKW];
    #pragma unroll
    for (int f = 0; f < 4; ++f) {
        const unsigned short* wrow = Wp + (g0 + f * 16 + col) * KTOT + w * (NKW * 32) + quad * 8;
        #pragma unroll
        for (int ks = 0; ks < NKW; ++ks)
            Bf[f][ks] = *(const uint4*)(wrow + ks * 32);
    }
    #pragma unroll
    for (int f = 0; f < 4; ++f) {
        #pragma unroll
        for (int ks = 0; ks < NKW; ++ks) {
            uint32_t c0 = Bf[f][ks].x, c1 = Bf[f][ks].y, c2 = Bf[f][ks].z, c3 = Bf[f][ks].w;
            asm volatile("" : "+v"(c0), "+v"(c1), "+v"(c2), "+v"(c3));
            Bf[f][ks].x = c0; Bf[f][ks].y = c1; Bf[f][ks].z = c2; Bf[f][ks].w = c3;
        }
    }

    const int bl = tid >> 4, ul = tid & 15;      // elementwise domain: 16 batch x 16 units
    const f32x4 bias = *(const f32x4*)(bp + g0 + ul * 4);
    float c = 0.f;                               // cell state, register-resident

    // Per-kstep A source offsets (frag never straddles the KS boundary: 32 | KS)
    int  offA[NKW];
    bool s0[NKW];
    #pragma unroll
    for (int ks = 0; ks < NKW; ++ks) {
        int kg = w * (NKW * 32) + ks * 32 + quad * 8;
        if (kg < KS) { s0[ks] = true;  offA[ks] = L0 ? (bA * (T_STEPS * 256) + kg) : (bA * 512 + kg); }
        else         { s0[ks] = false; offA[ks] = bA * 512 + (kg - KS); }
    }

    unsigned short* h0b[2] = { h00, h01 };
    unsigned short* h1b[2] = { h10, h11 };
    int rp = 0;

    for (int s = 0; s <= T_STEPS; ++s) {
        const bool active = L0 ? (s < T_STEPS) : (s >= 1);
        const unsigned short* h0r = h0b[rp];
        const unsigned short* h1r = h1b[rp];

        if (active) {
            const int t = L0 ? s : (s - 1);
            bf16x8 Af[NKW];
            if (L0) {
                const float* xb = x + t * 256;
                #pragma unroll
                for (int ks = 0; ks < NKW; ++ks) {
                    if (s0[ks]) {   // x source: fp32 -> bf16 on the fly
                        const float* p = xb + offA[ks];
                        float4 lo = *(const float4*)p;
                        float4 hi = *(const float4*)(p + 4);
                        bf16x8 v;
                        v[0]=(__bf16)lo.x; v[1]=(__bf16)lo.y; v[2]=(__bf16)lo.z; v[3]=(__bf16)lo.w;
                        v[4]=(__bf16)hi.x; v[5]=(__bf16)hi.y; v[6]=(__bf16)hi.z; v[7]=(__bf16)hi.w;
                        Af[ks] = v;
                    } else {
                        Af[ks] = __builtin_bit_cast(bf16x8, *(const uint4*)(h0r + offA[ks]));
                    }
                }
            } else {
                #pragma unroll
                for (int ks = 0; ks < NKW; ++ks) {
                    const unsigned short* p = (s0[ks] ? h0r : h1r) + offA[ks];
                    Af[ks] = __builtin_bit_cast(bf16x8, *(const uint4*)p);
                }
            }

            f32x4 acc[4] = { f32x4{0,0,0,0}, f32x4{0,0,0,0}, f32x4{0,0,0,0}, f32x4{0,0,0,0} };
            #pragma unroll
            for (int ks = 0; ks < NKW; ++ks) {
                #pragma unroll
                for (int f = 0; f < 4; ++f)
                    acc[f] = __builtin_amdgcn_mfma_f32_16x16x32_bf16(
                        Af[ks], __builtin_bit_cast(bf16x8, Bf[f][ks]), acc[f], 0, 0, 0);
            }
            // Dump partials: D row=quad*4+r (batch), col=f*16+col (packed gate)
            #pragma unroll
            for (int f = 0; f < 4; ++f) {
                #pragma unroll
                for (int r = 0; r < 4; ++r)
                    red[w][quad * 4 + r][f * 16 + col] = acc[f][r];
            }
        }
        __syncthreads();
        if (active) {
            f32x4 g = bias;
            #pragma unroll
            for (int ww = 0; ww < 4; ++ww)
                g += *(const f32x4*)&red[ww][bl][ul * 4];
            float ig = sigm(g[0]), fg = sigm(g[1]), gc = tanh_f(g[2]), og = sigm(g[3]);
            c = fg * c + ig * gc;
            float h = og * tanh_f(c);
            unsigned short* hw = L0 ? h0b[rp ^ 1] : h1b[rp ^ 1];
            hw[(b0 + bl) * 512 + ut0 + ul] = f2bf(h);     // plain store -> own L2
        }
        // all waves: drain own vmem (h stores now resident in this XCD's L2)
        asm volatile("s_waitcnt vmcnt(0)" ::: "memory");
        __syncthreads();
        // ONE release store per block: buffer_wbl2 (push dirty h to IF$) + flag.
        if (tid == 0)
            __hip_atomic_store(slots + myslot, (unsigned)(s + 1),
                               __ATOMIC_RELEASE, __HIP_MEMORY_SCOPE_AGENT);
        // wave0: parallel poll of all 64 group slots, then ONE acquire fence
        // (buffer_inv) so the next step's plain h loads refill from IF$.
        if (tid < 64) {
            const unsigned tgt = (unsigned)(s + 1);
            for (;;) {
                unsigned v = __hip_atomic_load(slots + tid, __ATOMIC_RELAXED,
                                               __HIP_MEMORY_SCOPE_AGENT);
                if (__all((int)(v >= tgt))) break;
                __builtin_amdgcn_s_sleep(1);
            }
            __builtin_amdgcn_fence(__ATOMIC_ACQUIRE, "agent");
        }
        __syncthreads();
        rp ^= 1;
    }
}

__global__ __launch_bounds__(NTHR, 2) void lstm_persistent(
    const float* __restrict__ x,
    const unsigned short* __restrict__ Wp0, const unsigned short* __restrict__ Wp1,
    const float* __restrict__ bp0, const float* __restrict__ bp1,
    unsigned short* __restrict__ hb, unsigned* __restrict__ cnt)
{
    __shared__ alignas(16) float red[4][16][68];   // 4 K-split waves x [16b][64g(+pad)]
    const int bid   = blockIdx.x;
    const int g     = bid & 7;          // batch-tile group (independent barrier domain)
    const int rest  = bid >> 3;         // 0..63: pid within group
    const int layer = rest & 1;
    const int ut    = rest >> 1;        // 0..31 unit-tile
    const int b0    = g * 16;
    const int ut0   = ut * 16;
    const int g0    = ut * 64;          // packed gate-row base (= ut0*4)
    const int tid   = threadIdx.x;
    const int w = tid >> 6, lane = tid & 63, col = lane & 15, quad = lane >> 4;

    unsigned* slots = cnt + g * 64;
    const int myslot = rest;

    unsigned short* h00 = hb;
    unsigned short* h01 = hb + 65536;
    unsigned short* h10 = hb + 131072;
    unsigned short* h11 = hb + 196608;

    if (layer == 0)
        run_layer<6, 768, 256, true >(b0, ut0, g0, w, col, quad, tid, x, Wp0, bp0, h00, h01, h10, h11, slots, myslot, red);
    else
        run_layer<8, 1024, 512, false>(b0, ut0, g0, w, col, quad, tid, x, Wp1, bp1, h00, h01, h10, h11, slots, myslot, red);
}

// ---- final FC head: logits[b] = h1_T[b,:] . fc_w + fc_b ----
__global__ void k_fc(const unsigned short* __restrict__ h1, const float* __restrict__ fcw,
                     const float* __restrict__ fcb, float* __restrict__ out)
{
    int b = threadIdx.x;
    if (b < 128) {
        const unsigned short* hr = h1 + b * 512;
        float acc = 0.f;
        for (int u = 0; u < 512; ++u) acc += bf2f(hr[u]) * fcw[u];
        out[b] = acc + fcb[0];
    }
}

extern "C" void kernel_launch(void* const* d_in, const int* in_sizes, int n_in,
                              void* d_out, int out_size, void* d_ws, size_t ws_size,
                              hipStream_t stream)
{
    const float* x    = (const float*)d_in[0];
    const float* Wih0 = (const float*)d_in[1];
    const float* Whh0 = (const float*)d_in[2];
    const float* bih0 = (const float*)d_in[3];
    const float* bhh0 = (const float*)d_in[4];
    const float* Wih1 = (const float*)d_in[5];
    const float* Whh1 = (const float*)d_in[6];
    const float* bih1 = (const float*)d_in[7];
    const float* bhh1 = (const float*)d_in[8];
    const float* fcw  = (const float*)d_in[9];
    const float* fcb  = (const float*)d_in[10];

    char* ws = (char*)d_ws;
    unsigned short* Wp0 = (unsigned short*)(ws + WS_WP0);
    unsigned short* Wp1 = (unsigned short*)(ws + WS_WP1);
    float* bp0 = (float*)(ws + WS_BP0);
    float* bp1 = (float*)(ws + WS_BP1);
    unsigned short* hb = (unsigned short*)(ws + WS_H);
    unsigned* cnt = (unsigned*)(ws + WS_CNT);

    const int npack = 2048 * 768 + 2048 * 1024;
    k_pack<<<(npack + 255) / 256, 256, 0, stream>>>(Wih0, Whh0, Wih1, Whh1, Wp0, Wp1);
    const int nmisc = 4096 + 262144 + CNT_U32;
    k_misc<<<(nmisc + 255) / 256, 256, 0, stream>>>(bih0, bhh0, bih1, bhh1, bp0, bp1, hb, cnt);

    lstm_persistent<<<NBLK, NTHR, 0, stream>>>(x, Wp0, Wp1, bp0, bp1, hb, cnt);

    // final h1 lands in ping-pong buffer index 1 (written at macro-step s=1024)
    k_fc<<<1, 128, 0, stream>>>(hb + 196608, fcw, fcb, (float*)d_out);
}